// Round 16
// baseline (43.899 us; speedup 1.0000x reference)
//
#include <hip/hip_runtime.h>
#include <hip/hip_fp8.h>
#include <stdint.h>

#define NPAIR 4096
#define N2    8192      // 2N rows
#define DIM   256
#define NTILE 4160      // 64x128 tiles covering strict upper triangle
// inputs pre-scaled by sqrt(log2(e)/T): acc == log2(e)/T * sim
#define SCALE_IN 1.6986436f

typedef long  f8frag;   // 8 fp8 elems = 2 VGPR (A/B operand of 16x16x32 fp8)
typedef float f32x4 __attribute__((ext_vector_type(4)));

static __device__ __forceinline__ uint8_t f2fp8(float f) {
    __hip_fp8_e4m3 v(f);                 // OCP e4m3fn, RNE saturating
    return *reinterpret_cast<uint8_t*>(&v);
}

// reps is stored FRAGMENT-TILED fp8: byte index of (row i, dim d) =
//   ((i>>4)*8 + (d>>5))*512 + ((d>>3)&3)*128 + (i&15)*8 + (d&7)
// an MFMA fragment (16 rows x 32 k; lane l -> row l&15, k-slot l>>4) is the
// contiguous 512B block at tile(i>>4, d>>5): lane l reads 8B at base + l*8.

// ---------------- Kernel A: normalize rows + positive dot + zero rowsum ----
__global__ __launch_bounds__(256) void normalize_kernel(
    const float* __restrict__ emb_i, const float* __restrict__ emb_j,
    uint8_t* __restrict__ reps, float* __restrict__ pdot,
    float* __restrict__ rowsum) {
    int i = blockIdx.x * 4 + (threadIdx.x >> 6);
    int l = threadIdx.x & 63;
    float4 a = ((const float4*)(emb_i + (size_t)i * DIM))[l];
    float4 b = ((const float4*)(emb_j + (size_t)i * DIM))[l];
    float si = a.x*a.x + a.y*a.y + a.z*a.z + a.w*a.w;
    float sj = b.x*b.x + b.y*b.y + b.z*b.z + b.w*b.w;
    float dp = a.x*b.x + a.y*b.y + a.z*b.z + a.w*b.w;
    #pragma unroll
    for (int off = 32; off; off >>= 1) {
        si += __shfl_xor(si, off);
        sj += __shfl_xor(sj, off);
        dp += __shfl_xor(dp, off);
    }
    float ri = 1.0f / fmaxf(sqrtf(si), 1e-12f);
    float rj = 1.0f / fmaxf(sqrtf(sj), 1e-12f);
    float riS = ri * SCALE_IN, rjS = rj * SCALE_IN;

    uchar4 ua, ub;
    ua.x = f2fp8(a.x * riS); ua.y = f2fp8(a.y * riS);
    ua.z = f2fp8(a.z * riS); ua.w = f2fp8(a.w * riS);
    ub.x = f2fp8(b.x * rjS); ub.y = f2fp8(b.y * rjS);
    ub.z = f2fp8(b.z * rjS); ub.w = f2fp8(b.w * rjS);

    int ii = i + NPAIR;
    int idxA = (((i  >> 4) * 8 + (l >> 3)) * 512) + ((l >> 1) & 3) * 128
             + (i  & 15) * 8 + (l & 1) * 4;
    int idxB = (((ii >> 4) * 8 + (l >> 3)) * 512) + ((l >> 1) & 3) * 128
             + (ii & 15) * 8 + (l & 1) * 4;
    *(uchar4*)(reps + idxA) = ua;
    *(uchar4*)(reps + idxB) = ub;

    if (l == 0) pdot[i] = dp * ri * rj;       // positives fp32, unscaled
    if (l < 2)  rowsum[2 * i + l] = 0.f;
}

// ---------- Kernel B: BARRIER-FREE per-wave 64x128 triangle tiles ----------
// One wave per 64(row)x128(col) tile; A-panel (4 frag-rows) shared across
// both 64-col halves -> 48 KB loads per tile-pair vs 64 KB as two 64x64
// tiles; 32 independent MFMAs per kw phase hide L2 latency in-wave.
// Tiles (I,J) with d2 = J - (I>>1) >= 0 cover the strict upper triangle;
// count C(d2) = d2*(129-d2) before diagonal d2 (anti-diagonal order).
// d2 == 0 tiles straddle the main diagonal -> strict mask grow<gcol;
// d2 >= 1 tiles are fully strictly-upper -> unmasked. Each computed element
// adds exp to BOTH rowsum[row] and rowsum[col] (each unordered pair is
// computed exactly once; symmetry completes the masked row sums).
// No __shared__, no __syncthreads, no setprio (suspected issue-starvation).
__global__ __launch_bounds__(256, 2) void simexp_kernel(
    const uint8_t* __restrict__ reps, float* __restrict__ rowsum) {
    int t = threadIdx.x;
    int l = t & 63;

    int idx = blockIdx.x * 4 + (t >> 6);
    // decode: d2 = (129 - sqrt(129^2 - 4*idx)) / 2, then exact fix-up
    int d2 = (int)((129.0f - sqrtf(16641.0f - 4.0f * (float)idx)) * 0.5f);
    while (d2 * (129 - d2) > idx) --d2;
    while ((d2 + 1) * (128 - d2) <= idx) ++d2;
    int I = idx - d2 * (129 - d2);      // 0 .. 2*(64-d2)-1
    int J = (I >> 1) + d2;
    int brow = I * 64;
    int bcol = J * 128;
    int R0A = I * 4;                    // + q (4 frag-rows of 16)
    int R0B = J * 8;                    // + q (8 frag-rows of 16)

    f32x4 acc[4][8];
    #pragma unroll
    for (int mi = 0; mi < 4; ++mi)
        #pragma unroll
        for (int ni = 0; ni < 8; ++ni)
            acc[mi][ni] = (f32x4){0.f, 0.f, 0.f, 0.f};

    #define LOADF(dstA, dstB, kw)                                              \
        _Pragma("unroll")                                                      \
        for (int q = 0; q < 4; ++q)                                            \
            dstA[q] = ((const f8frag*)(reps +                                  \
                       (size_t)(((R0A + q) * 8 + (kw)) * 512)))[l];            \
        _Pragma("unroll")                                                      \
        for (int q = 0; q < 8; ++q)                                            \
            dstB[q] = ((const f8frag*)(reps +                                  \
                       (size_t)(((R0B + q) * 8 + (kw)) * 512)))[l];
    #define MM(a, b)                                                           \
        _Pragma("unroll")                                                      \
        for (int mi = 0; mi < 4; ++mi)                                         \
            _Pragma("unroll")                                                  \
            for (int ni = 0; ni < 8; ++ni)                                     \
                acc[mi][ni] = __builtin_amdgcn_mfma_f32_16x16x32_fp8_fp8(      \
                    a[mi], b[ni], acc[mi][ni], 0, 0, 0);

    f8frag a0[4], b0[8], a1[4], b1[8];
    LOADF(a0, b0, 0);
    LOADF(a1, b1, 1);
    #pragma unroll
    for (int kw = 0; kw < 8; ++kw) {        // 8 k-windows of 32
        if ((kw & 1) == 0) {
            MM(a0, b0);
            if (kw + 2 < 8) { LOADF(a0, b0, kw + 2); }
        } else {
            MM(a1, b1);
            if (kw + 2 < 8) { LOADF(a1, b1, kw + 2); }
        }
    }
    #undef LOADF
    #undef MM

    // Epilogue. C/D: col = lane&15, row = (lane>>4)*4 + j  [m89/m91]
    // acc already == log2(e)/T * sim -> bare exp2f.
    int frow = l & 15;
    int k16  = l >> 4;
    float csum[8] = {0.f, 0.f, 0.f, 0.f, 0.f, 0.f, 0.f, 0.f};
    float rv = 0.f;

    if (d2 != 0) {                  // fully strict-upper: unmasked
        #pragma unroll
        for (int mi = 0; mi < 4; ++mi) {
            #pragma unroll
            for (int j = 0; j < 4; ++j) {
                float rp = 0.f;
                #pragma unroll
                for (int ni = 0; ni < 8; ++ni) {
                    float e = exp2f(acc[mi][ni][j]);
                    csum[ni] += e;
                    rp += e;
                }
                rp += __shfl_xor(rp, 1);
                rp += __shfl_xor(rp, 2);
                rp += __shfl_xor(rp, 4);
                rp += __shfl_xor(rp, 8);
                rv = (frow == mi * 4 + j) ? rp : rv;
            }
        }
    } else {                        // straddling tile: strict mask grow<gcol
        int rbase = brow + k16 * 4;
        int cb    = bcol + frow;
        #pragma unroll
        for (int mi = 0; mi < 4; ++mi) {
            #pragma unroll
            for (int j = 0; j < 4; ++j) {
                int grow = rbase + mi * 16 + j;
                float rp = 0.f;
                #pragma unroll
                for (int ni = 0; ni < 8; ++ni) {
                    float e = exp2f(acc[mi][ni][j]);
                    e = (grow < cb + ni * 16) ? e : 0.f;
                    csum[ni] += e;
                    rp += e;
                }
                rp += __shfl_xor(rp, 1);
                rp += __shfl_xor(rp, 2);
                rp += __shfl_xor(rp, 4);
                rp += __shfl_xor(rp, 8);
                rv = (frow == mi * 4 + j) ? rp : rv;
            }
        }
    }

    // column totals: reduce over k16 groups; 2 col atomics + 1 row atomic/lane
    #pragma unroll
    for (int ni = 0; ni < 8; ++ni) {
        csum[ni] += __shfl_xor(csum[ni], 16);
        csum[ni] += __shfl_xor(csum[ni], 32);
    }
    float cv = csum[0], cv2 = csum[4];
    #pragma unroll
    for (int v = 1; v < 4; ++v) {               // static-index selects
        cv  = (k16 == v) ? csum[v]     : cv;
        cv2 = (k16 == v) ? csum[v + 4] : cv2;
    }
    atomicAdd(&rowsum[bcol + k16 * 16 + frow], cv);        // cols 0..63
    atomicAdd(&rowsum[bcol + 64 + k16 * 16 + frow], cv2);  // cols 64..127

    int grow = brow + (frow >> 2) * 16 + k16 * 4 + (frow & 3);
    atomicAdd(&rowsum[grow], rv);               // 64 disjoint rows (0 if masked)
}

// ---------------- Kernel C: finalize ----------------
__global__ __launch_bounds__(256) void finalize_kernel(
    const float* __restrict__ rowsum, const float* __restrict__ pdot,
    float* __restrict__ out) {
    int t = threadIdx.x;
    __shared__ float reds[4], redp[4];
    const float4* rs4 = (const float4*)rowsum;
    const float4* pd4 = (const float4*)pdot;
    float s = 0.f, p = 0.f;
    for (int r = t; r < N2 / 4; r += 256) {
        float4 v = rs4[r];
        s += __logf(v.x) + __logf(v.y) + __logf(v.z) + __logf(v.w);
    }
    for (int r = t; r < NPAIR / 4; r += 256) {
        float4 v = pd4[r];
        p += v.x + v.y + v.z + v.w;
    }
    #pragma unroll
    for (int off = 32; off; off >>= 1) {
        s += __shfl_xor(s, off);
        p += __shfl_xor(p, off);
    }
    if ((t & 63) == 0) { reds[t >> 6] = s; redp[t >> 6] = p; }
    __syncthreads();
    if (t == 0) {
        float S = reds[0] + reds[1] + reds[2] + reds[3];
        float P = redp[0] + redp[1] + redp[2] + redp[3];
        // loss = (sum log D - (2/T)*2*sum(dp)) / 2N ; (2/T)*2 folded: 4*P
        out[0] = (S - 4.0f * P) / (float)N2;
    }
}

extern "C" void kernel_launch(void* const* d_in, const int* in_sizes, int n_in,
                              void* d_out, int out_size, void* d_ws, size_t ws_size,
                              hipStream_t stream) {
    const float* emb_i = (const float*)d_in[0];
    const float* emb_j = (const float*)d_in[1];
    float* out = (float*)d_out;

    char* ws = (char*)d_ws;
    float*    rowsum = (float*)ws;                    // 8192 * 4 B
    float*    pdot   = (float*)(ws + 32768);          // 4096 * 4 B
    uint8_t*  reps   = (uint8_t*)(ws + 65536);        // 8192*256 B (fp8 tiled)

    normalize_kernel<<<NPAIR / 4, 256, 0, stream>>>(emb_i, emb_j, reps,
                                                    pdot, rowsum);
    simexp_kernel<<<NTILE / 4, 256, 0, stream>>>(reps, rowsum);
    finalize_kernel<<<1, 256, 0, stream>>>(rowsum, pdot, out);
}

// Round 17
// 38.065 us; speedup vs baseline: 1.1533x; 1.1533x over previous
//
#include <hip/hip_runtime.h>
#include <hip/hip_fp8.h>
#include <stdint.h>

#define NPAIR 4096
#define N2    8192      // 2N rows
#define DIM   256
#define NTILE 8256      // 128*129/2 upper-triangle 64x64 tiles
// inputs pre-scaled by sqrt(log2(e)/T): acc == log2(e)/T * sim
#define SCALE_IN 1.6986436f

typedef long  f8frag;   // 8 fp8 elems = 2 VGPR (A/B operand of 16x16x32 fp8)
typedef float f32x4 __attribute__((ext_vector_type(4)));

static __device__ __forceinline__ uint8_t f2fp8(float f) {
    __hip_fp8_e4m3 v(f);                 // OCP e4m3fn, RNE saturating
    return *reinterpret_cast<uint8_t*>(&v);
}

// reps is stored FRAGMENT-TILED fp8: byte index of (row i, dim d) =
//   ((i>>4)*8 + (d>>5))*512 + ((d>>3)&3)*128 + (i&15)*8 + (d&7)
// an MFMA fragment (16 rows x 32 k; lane l -> row l&15, k-slot l>>4) is the
// contiguous 512B block at tile(i>>4, d>>5): lane l reads 8B at base + l*8.

// ---------------- Kernel A: normalize rows + positive dot + zero rowsum ----
__global__ __launch_bounds__(256) void normalize_kernel(
    const float* __restrict__ emb_i, const float* __restrict__ emb_j,
    uint8_t* __restrict__ reps, float* __restrict__ pdot,
    float* __restrict__ rowsum) {
    int i = blockIdx.x * 4 + (threadIdx.x >> 6);
    int l = threadIdx.x & 63;
    float4 a = ((const float4*)(emb_i + (size_t)i * DIM))[l];
    float4 b = ((const float4*)(emb_j + (size_t)i * DIM))[l];
    float si = a.x*a.x + a.y*a.y + a.z*a.z + a.w*a.w;
    float sj = b.x*b.x + b.y*b.y + b.z*b.z + b.w*b.w;
    float dp = a.x*b.x + a.y*b.y + a.z*b.z + a.w*b.w;
    #pragma unroll
    for (int off = 32; off; off >>= 1) {
        si += __shfl_xor(si, off);
        sj += __shfl_xor(sj, off);
        dp += __shfl_xor(dp, off);
    }
    float ri = 1.0f / fmaxf(sqrtf(si), 1e-12f);
    float rj = 1.0f / fmaxf(sqrtf(sj), 1e-12f);
    float riS = ri * SCALE_IN, rjS = rj * SCALE_IN;

    uchar4 ua, ub;
    ua.x = f2fp8(a.x * riS); ua.y = f2fp8(a.y * riS);
    ua.z = f2fp8(a.z * riS); ua.w = f2fp8(a.w * riS);
    ub.x = f2fp8(b.x * rjS); ub.y = f2fp8(b.y * rjS);
    ub.z = f2fp8(b.z * rjS); ub.w = f2fp8(b.w * rjS);

    int ii = i + NPAIR;
    int idxA = (((i  >> 4) * 8 + (l >> 3)) * 512) + ((l >> 1) & 3) * 128
             + (i  & 15) * 8 + (l & 1) * 4;
    int idxB = (((ii >> 4) * 8 + (l >> 3)) * 512) + ((l >> 1) & 3) * 128
             + (ii & 15) * 8 + (l & 1) * 4;
    *(uchar4*)(reps + idxA) = ua;
    *(uchar4*)(reps + idxB) = ub;

    if (l == 0) pdot[i] = dp * ri * rj;       // positives fp32, unscaled
    if (l < 2)  rowsum[2 * i + l] = 0.f;
}

// ---------- Kernel B: BARRIER-FREE per-wave 64x64 triangle tiles ----------
// r15 structure (best: 39.08us) with ONE change: the off-diagonal row-sum
// reduction is a butterfly multi-reduce (15 shuffles for all 16 row sums,
// each landing on lane frow==mi*4+j) instead of 16x separate 4-stage
// reductions (64 shuffles). Atomic pattern identical to r15.
__global__ __launch_bounds__(256, 4) void simexp_kernel(
    const uint8_t* __restrict__ reps, float* __restrict__ rowsum) {
    int t = threadIdx.x;
    int l = t & 63;

    // anti-diagonal decode over n=128 tile grid: C(d) = d*(257-d)/2
    int idx = blockIdx.x * 4 + (t >> 6);
    int d = (int)((257.0f - sqrtf(257.0f * 257.0f - 8.0f * (float)idx)) * 0.5f);
    while (d * (257 - d) / 2 > idx) --d;
    while ((d + 1) * (256 - d) / 2 <= idx) ++d;
    int i0 = idx - d * (257 - d) / 2;
    int brow = i0 * 64;
    int bcol = (i0 + d) * 64;
    int R0A = i0 * 4;
    int R0B = (i0 + d) * 4;

    f32x4 acc[4][4];
    #pragma unroll
    for (int mi = 0; mi < 4; ++mi)
        #pragma unroll
        for (int ni = 0; ni < 4; ++ni)
            acc[mi][ni] = (f32x4){0.f, 0.f, 0.f, 0.f};

    #define LOADF(dstA, dstB, kw)                                              \
        _Pragma("unroll")                                                      \
        for (int q = 0; q < 4; ++q) {                                          \
            dstA[q] = ((const f8frag*)(reps +                                  \
                       (size_t)(((R0A + q) * 8 + (kw)) * 512)))[l];            \
            dstB[q] = ((const f8frag*)(reps +                                  \
                       (size_t)(((R0B + q) * 8 + (kw)) * 512)))[l];            \
        }
    #define MM(a, b)                                                           \
        __builtin_amdgcn_s_setprio(1);                                         \
        _Pragma("unroll")                                                      \
        for (int mi = 0; mi < 4; ++mi)                                         \
            _Pragma("unroll")                                                  \
            for (int ni = 0; ni < 4; ++ni)                                     \
                acc[mi][ni] = __builtin_amdgcn_mfma_f32_16x16x32_fp8_fp8(      \
                    a[mi], b[ni], acc[mi][ni], 0, 0, 0);                       \
        __builtin_amdgcn_s_setprio(0);

    f8frag a0[4], b0[4], a1[4], b1[4];
    LOADF(a0, b0, 0);
    LOADF(a1, b1, 1);
    #pragma unroll
    for (int kw = 0; kw < 8; ++kw) {
        if ((kw & 1) == 0) {
            MM(a0, b0);
            if (kw + 2 < 8) { LOADF(a0, b0, kw + 2); }
        } else {
            MM(a1, b1);
            if (kw + 2 < 8) { LOADF(a1, b1, kw + 2); }
        }
    }
    #undef LOADF
    #undef MM

    // Epilogue. C/D: col = lane&15, row = (lane>>4)*4 + j  [m89/m91]
    // acc already == log2(e)/T * sim -> bare exp2f.
    int frow = l & 15;
    int k16  = l >> 4;
    float csum[4] = {0.f, 0.f, 0.f, 0.f};

    if (d != 0) {                   // off-diagonal: unmasked, rows + cols
        float rpar[16];
        #pragma unroll
        for (int mi = 0; mi < 4; ++mi) {
            #pragma unroll
            for (int j = 0; j < 4; ++j) {
                float rp = 0.f;
                #pragma unroll
                for (int ni = 0; ni < 4; ++ni) {
                    float e = exp2f(acc[mi][ni][j]);
                    csum[ni] += e;
                    rp += e;
                }
                rpar[mi * 4 + j] = rp;
            }
        }
        // butterfly multi-reduce over the 16-lane group: after stage m,
        // lane p holds values v (v mod 2m == p mod 2m) summed over 2m lanes.
        // Final: lane frow holds full row sum for v = frow. 15 shuffles.
        bool s0 = (frow & 1);
        float w8[8];
        #pragma unroll
        for (int i = 0; i < 8; ++i) {
            float keep = s0 ? rpar[2 * i + 1] : rpar[2 * i];
            float send = s0 ? rpar[2 * i]     : rpar[2 * i + 1];
            w8[i] = keep + __shfl_xor(send, 1);
        }
        bool s1 = (frow & 2);
        float w4[4];
        #pragma unroll
        for (int i = 0; i < 4; ++i) {
            float keep = s1 ? w8[2 * i + 1] : w8[2 * i];
            float send = s1 ? w8[2 * i]     : w8[2 * i + 1];
            w4[i] = keep + __shfl_xor(send, 2);
        }
        bool s2 = (frow & 4);
        float w2[2];
        #pragma unroll
        for (int i = 0; i < 2; ++i) {
            float keep = s2 ? w4[2 * i + 1] : w4[2 * i];
            float send = s2 ? w4[2 * i]     : w4[2 * i + 1];
            w2[i] = keep + __shfl_xor(send, 4);
        }
        bool s3 = (frow & 8);
        float keep = s3 ? w2[1] : w2[0];
        float send = s3 ? w2[0] : w2[1];
        float rv = keep + __shfl_xor(send, 8);

        #pragma unroll
        for (int ni = 0; ni < 4; ++ni) {
            csum[ni] += __shfl_xor(csum[ni], 16);
            csum[ni] += __shfl_xor(csum[ni], 32);
        }
        float cv = csum[0];
        #pragma unroll
        for (int v = 1; v < 4; ++v) cv = (k16 == v) ? csum[v] : cv;
        atomicAdd(&rowsum[bcol + k16 * 16 + frow], cv);  // 64 disjoint cols
        int grow = brow + (frow >> 2) * 16 + k16 * 4 + (frow & 3);
        atomicAdd(&rowsum[grow], rv);                    // 64 disjoint rows
    } else {                        // diagonal tile: masked, cols only
        int rbase = brow + k16 * 4;
        int cb    = bcol + frow;
        #pragma unroll
        for (int mi = 0; mi < 4; ++mi) {
            #pragma unroll
            for (int j = 0; j < 4; ++j) {
                int grow = rbase + mi * 16 + j;
                #pragma unroll
                for (int ni = 0; ni < 4; ++ni) {
                    float e = exp2f(acc[mi][ni][j]);
                    e = (grow == cb + ni * 16) ? 0.f : e;
                    csum[ni] += e;
                }
            }
        }
        #pragma unroll
        for (int ni = 0; ni < 4; ++ni) {
            csum[ni] += __shfl_xor(csum[ni], 16);
            csum[ni] += __shfl_xor(csum[ni], 32);
        }
        float cv = csum[0];
        #pragma unroll
        for (int v = 1; v < 4; ++v) cv = (k16 == v) ? csum[v] : cv;
        atomicAdd(&rowsum[bcol + k16 * 16 + frow], cv);
    }
}

// ---------------- Kernel C: finalize ----------------
__global__ __launch_bounds__(256) void finalize_kernel(
    const float* __restrict__ rowsum, const float* __restrict__ pdot,
    float* __restrict__ out) {
    int t = threadIdx.x;
    __shared__ float reds[4], redp[4];
    const float4* rs4 = (const float4*)rowsum;
    const float4* pd4 = (const float4*)pdot;
    float s = 0.f, p = 0.f;
    for (int r = t; r < N2 / 4; r += 256) {
        float4 v = rs4[r];
        s += __logf(v.x) + __logf(v.y) + __logf(v.z) + __logf(v.w);
    }
    for (int r = t; r < NPAIR / 4; r += 256) {
        float4 v = pd4[r];
        p += v.x + v.y + v.z + v.w;
    }
    #pragma unroll
    for (int off = 32; off; off >>= 1) {
        s += __shfl_xor(s, off);
        p += __shfl_xor(p, off);
    }
    if ((t & 63) == 0) { reds[t >> 6] = s; redp[t >> 6] = p; }
    __syncthreads();
    if (t == 0) {
        float S = reds[0] + reds[1] + reds[2] + reds[3];
        float P = redp[0] + redp[1] + redp[2] + redp[3];
        // loss = (sum log D - (2/T)*2*sum(dp)) / 2N ; (2/T)*2 folded: 4*P
        out[0] = (S - 4.0f * P) / (float)N2;
    }
}

extern "C" void kernel_launch(void* const* d_in, const int* in_sizes, int n_in,
                              void* d_out, int out_size, void* d_ws, size_t ws_size,
                              hipStream_t stream) {
    const float* emb_i = (const float*)d_in[0];
    const float* emb_j = (const float*)d_in[1];
    float* out = (float*)d_out;

    char* ws = (char*)d_ws;
    float*    rowsum = (float*)ws;                    // 8192 * 4 B
    float*    pdot   = (float*)(ws + 32768);          // 4096 * 4 B
    uint8_t*  reps   = (uint8_t*)(ws + 65536);        // 8192*256 B (fp8 tiled)

    normalize_kernel<<<NPAIR / 4, 256, 0, stream>>>(emb_i, emb_j, reps,
                                                    pdot, rowsum);
    simexp_kernel<<<NTILE / 4, 256, 0, stream>>>(reps, rowsum);
    finalize_kernel<<<1, 256, 0, stream>>>(rowsum, pdot, out);
}

// Round 18
// 38.056 us; speedup vs baseline: 1.1535x; 1.0002x over previous
//
#include <hip/hip_runtime.h>
#include <hip/hip_fp8.h>
#include <stdint.h>

#define NPAIR 4096
#define N2    8192      // 2N rows
#define DIM   256
#define NQUAD 2080      // 64*65/2 upper-triangle 128x128 quads (2x2 tiles)
// inputs pre-scaled by sqrt(log2(e)/T): acc == log2(e)/T * sim
#define SCALE_IN 1.6986436f

typedef long  f8frag;   // 8 fp8 elems = 2 VGPR (A/B operand of 16x16x32 fp8)
typedef float f32x4 __attribute__((ext_vector_type(4)));

static __device__ __forceinline__ uint8_t f2fp8(float f) {
    __hip_fp8_e4m3 v(f);                 // OCP e4m3fn, RNE saturating
    return *reinterpret_cast<uint8_t*>(&v);
}

// reps is stored FRAGMENT-TILED fp8: byte index of (row i, dim d) =
//   ((i>>4)*8 + (d>>5))*512 + ((d>>3)&3)*128 + (i&15)*8 + (d&7)
// an MFMA fragment (16 rows x 32 k; lane l -> row l&15, k-slot l>>4) is the
// contiguous 512B block at tile(i>>4, d>>5): lane l reads 8B at base + l*8.

// ---------------- Kernel A: normalize rows + positive dot + zero rowsum ----
__global__ __launch_bounds__(256) void normalize_kernel(
    const float* __restrict__ emb_i, const float* __restrict__ emb_j,
    uint8_t* __restrict__ reps, float* __restrict__ pdot,
    float* __restrict__ rowsum) {
    int i = blockIdx.x * 4 + (threadIdx.x >> 6);
    int l = threadIdx.x & 63;
    float4 a = ((const float4*)(emb_i + (size_t)i * DIM))[l];
    float4 b = ((const float4*)(emb_j + (size_t)i * DIM))[l];
    float si = a.x*a.x + a.y*a.y + a.z*a.z + a.w*a.w;
    float sj = b.x*b.x + b.y*b.y + b.z*b.z + b.w*b.w;
    float dp = a.x*b.x + a.y*b.y + a.z*b.z + a.w*b.w;
    #pragma unroll
    for (int off = 32; off; off >>= 1) {
        si += __shfl_xor(si, off);
        sj += __shfl_xor(sj, off);
        dp += __shfl_xor(dp, off);
    }
    float ri = 1.0f / fmaxf(sqrtf(si), 1e-12f);
    float rj = 1.0f / fmaxf(sqrtf(sj), 1e-12f);
    float riS = ri * SCALE_IN, rjS = rj * SCALE_IN;

    uchar4 ua, ub;
    ua.x = f2fp8(a.x * riS); ua.y = f2fp8(a.y * riS);
    ua.z = f2fp8(a.z * riS); ua.w = f2fp8(a.w * riS);
    ub.x = f2fp8(b.x * rjS); ub.y = f2fp8(b.y * rjS);
    ub.z = f2fp8(b.z * rjS); ub.w = f2fp8(b.w * rjS);

    int ii = i + NPAIR;
    int idxA = (((i  >> 4) * 8 + (l >> 3)) * 512) + ((l >> 1) & 3) * 128
             + (i  & 15) * 8 + (l & 1) * 4;
    int idxB = (((ii >> 4) * 8 + (l >> 3)) * 512) + ((l >> 1) & 3) * 128
             + (ii & 15) * 8 + (l & 1) * 4;
    *(uchar4*)(reps + idxA) = ua;
    *(uchar4*)(reps + idxB) = ub;

    if (l == 0) pdot[i] = dp * ri * rj;       // positives fp32, unscaled
    if (l < 2)  rowsum[2 * i + l] = 0.f;
}

// ---------- Kernel B: quad-mapped BARRIER-FREE per-wave 64x64 tiles -------
// Each 4-wave block owns a 2x2 QUAD of 64x64 tiles (128x128 super-tile on
// the upper triangle, 2080 quads in anti-diagonal order): wave w computes
// tile (2qI + (w>>1), 2qJ + (w&1)). Waves sharing a row-/col-tile read the
// SAME fragment panels in near-lockstep -> second reader hits per-CU L1
// (per-kw shared set 8 KB << 32 KB L1): L2 traffic and latency ~halve with
// no LDS and no barriers. Inner body identical to r17 (best): fp8 MFMA,
// depth-2 register pipeline, setprio, butterfly row multi-reduce, 2 atomics
// per lane. Diagonal quads idle their below-diagonal wave (64/8320 waves).
__global__ __launch_bounds__(256, 4) void simexp_kernel(
    const uint8_t* __restrict__ reps, float* __restrict__ rowsum) {
    int t = threadIdx.x;
    int l = t & 63;
    int w = t >> 6;

    // anti-diagonal quad decode over n=64 grid: C(qd) = qd*(129-qd)/2
    int q = blockIdx.x;
    int qd = (int)((129.0f - sqrtf(16641.0f - 8.0f * (float)q)) * 0.5f);
    while (qd * (129 - qd) / 2 > q) --qd;
    while ((qd + 1) * (128 - qd) / 2 <= q) ++qd;
    int qI = q - qd * (129 - qd) / 2;
    int qJ = qI + qd;

    int rT = 2 * qI + (w >> 1);         // row-tile (16-row frag rows: rT*4+)
    int cT = 2 * qJ + (w & 1);          // col-tile
    int d  = cT - rT;
    if (d < 0) return;                  // below diagonal (diag quads only)

    int brow = rT * 64;
    int bcol = cT * 64;
    int R0A  = rT * 4;
    int R0B  = cT * 4;

    f32x4 acc[4][4];
    #pragma unroll
    for (int mi = 0; mi < 4; ++mi)
        #pragma unroll
        for (int ni = 0; ni < 4; ++ni)
            acc[mi][ni] = (f32x4){0.f, 0.f, 0.f, 0.f};

    #define LOADF(dstA, dstB, kw)                                              \
        _Pragma("unroll")                                                      \
        for (int qq = 0; qq < 4; ++qq) {                                       \
            dstA[qq] = ((const f8frag*)(reps +                                 \
                        (size_t)(((R0A + qq) * 8 + (kw)) * 512)))[l];          \
            dstB[qq] = ((const f8frag*)(reps +                                 \
                        (size_t)(((R0B + qq) * 8 + (kw)) * 512)))[l];          \
        }
    #define MM(a, b)                                                           \
        __builtin_amdgcn_s_setprio(1);                                         \
        _Pragma("unroll")                                                      \
        for (int mi = 0; mi < 4; ++mi)                                         \
            _Pragma("unroll")                                                  \
            for (int ni = 0; ni < 4; ++ni)                                     \
                acc[mi][ni] = __builtin_amdgcn_mfma_f32_16x16x32_fp8_fp8(      \
                    a[mi], b[ni], acc[mi][ni], 0, 0, 0);                       \
        __builtin_amdgcn_s_setprio(0);

    f8frag a0[4], b0[4], a1[4], b1[4];
    LOADF(a0, b0, 0);
    LOADF(a1, b1, 1);
    #pragma unroll
    for (int kw = 0; kw < 8; ++kw) {
        if ((kw & 1) == 0) {
            MM(a0, b0);
            if (kw + 2 < 8) { LOADF(a0, b0, kw + 2); }
        } else {
            MM(a1, b1);
            if (kw + 2 < 8) { LOADF(a1, b1, kw + 2); }
        }
    }
    #undef LOADF
    #undef MM

    // Epilogue. C/D: col = lane&15, row = (lane>>4)*4 + j  [m89/m91]
    // acc already == log2(e)/T * sim -> bare exp2f.
    int frow = l & 15;
    int k16  = l >> 4;
    float csum[4] = {0.f, 0.f, 0.f, 0.f};

    if (d != 0) {                   // off-diagonal: unmasked, rows + cols
        float rpar[16];
        #pragma unroll
        for (int mi = 0; mi < 4; ++mi) {
            #pragma unroll
            for (int j = 0; j < 4; ++j) {
                float rp = 0.f;
                #pragma unroll
                for (int ni = 0; ni < 4; ++ni) {
                    float e = exp2f(acc[mi][ni][j]);
                    csum[ni] += e;
                    rp += e;
                }
                rpar[mi * 4 + j] = rp;
            }
        }
        // butterfly multi-reduce: 15 shuffles; lane frow ends with row sum
        // for value v == frow (rows of this wave's 64-row strip).
        bool s0 = (frow & 1);
        float w8[8];
        #pragma unroll
        for (int i = 0; i < 8; ++i) {
            float keep = s0 ? rpar[2 * i + 1] : rpar[2 * i];
            float send = s0 ? rpar[2 * i]     : rpar[2 * i + 1];
            w8[i] = keep + __shfl_xor(send, 1);
        }
        bool s1 = (frow & 2);
        float w4[4];
        #pragma unroll
        for (int i = 0; i < 4; ++i) {
            float keep = s1 ? w8[2 * i + 1] : w8[2 * i];
            float send = s1 ? w8[2 * i]     : w8[2 * i + 1];
            w4[i] = keep + __shfl_xor(send, 2);
        }
        bool s2 = (frow & 4);
        float w2[2];
        #pragma unroll
        for (int i = 0; i < 2; ++i) {
            float keep = s2 ? w4[2 * i + 1] : w4[2 * i];
            float send = s2 ? w4[2 * i]     : w4[2 * i + 1];
            w2[i] = keep + __shfl_xor(send, 4);
        }
        bool s3 = (frow & 8);
        float keep = s3 ? w2[1] : w2[0];
        float send = s3 ? w2[0] : w2[1];
        float rv = keep + __shfl_xor(send, 8);

        #pragma unroll
        for (int ni = 0; ni < 4; ++ni) {
            csum[ni] += __shfl_xor(csum[ni], 16);
            csum[ni] += __shfl_xor(csum[ni], 32);
        }
        float cv = csum[0];
        #pragma unroll
        for (int v = 1; v < 4; ++v) cv = (k16 == v) ? csum[v] : cv;
        atomicAdd(&rowsum[bcol + k16 * 16 + frow], cv);  // 64 disjoint cols
        int grow = brow + (frow >> 2) * 16 + k16 * 4 + (frow & 3);
        atomicAdd(&rowsum[grow], rv);                    // 64 disjoint rows
    } else {                        // diagonal tile: masked, cols only
        int rbase = brow + k16 * 4;
        int cb    = bcol + frow;
        #pragma unroll
        for (int mi = 0; mi < 4; ++mi) {
            #pragma unroll
            for (int j = 0; j < 4; ++j) {
                int grow = rbase + mi * 16 + j;
                #pragma unroll
                for (int ni = 0; ni < 4; ++ni) {
                    float e = exp2f(acc[mi][ni][j]);
                    e = (grow == cb + ni * 16) ? 0.f : e;
                    csum[ni] += e;
                }
            }
        }
        #pragma unroll
        for (int ni = 0; ni < 4; ++ni) {
            csum[ni] += __shfl_xor(csum[ni], 16);
            csum[ni] += __shfl_xor(csum[ni], 32);
        }
        float cv = csum[0];
        #pragma unroll
        for (int v = 1; v < 4; ++v) cv = (k16 == v) ? csum[v] : cv;
        atomicAdd(&rowsum[bcol + k16 * 16 + frow], cv);
    }
}

// ---------------- Kernel C: finalize ----------------
__global__ __launch_bounds__(256) void finalize_kernel(
    const float* __restrict__ rowsum, const float* __restrict__ pdot,
    float* __restrict__ out) {
    int t = threadIdx.x;
    __shared__ float reds[4], redp[4];
    const float4* rs4 = (const float4*)rowsum;
    const float4* pd4 = (const float4*)pdot;
    float s = 0.f, p = 0.f;
    for (int r = t; r < N2 / 4; r += 256) {
        float4 v = rs4[r];
        s += __logf(v.x) + __logf(v.y) + __logf(v.z) + __logf(v.w);
    }
    for (int r = t; r < NPAIR / 4; r += 256) {
        float4 v = pd4[r];
        p += v.x + v.y + v.z + v.w;
    }
    #pragma unroll
    for (int off = 32; off; off >>= 1) {
        s += __shfl_xor(s, off);
        p += __shfl_xor(p, off);
    }
    if ((t & 63) == 0) { reds[t >> 6] = s; redp[t >> 6] = p; }
    __syncthreads();
    if (t == 0) {
        float S = reds[0] + reds[1] + reds[2] + reds[3];
        float P = redp[0] + redp[1] + redp[2] + redp[3];
        // loss = (sum log D - (2/T)*2*sum(dp)) / 2N ; (2/T)*2 folded: 4*P
        out[0] = (S - 4.0f * P) / (float)N2;
    }
}

extern "C" void kernel_launch(void* const* d_in, const int* in_sizes, int n_in,
                              void* d_out, int out_size, void* d_ws, size_t ws_size,
                              hipStream_t stream) {
    const float* emb_i = (const float*)d_in[0];
    const float* emb_j = (const float*)d_in[1];
    float* out = (float*)d_out;

    char* ws = (char*)d_ws;
    float*    rowsum = (float*)ws;                    // 8192 * 4 B
    float*    pdot   = (float*)(ws + 32768);          // 4096 * 4 B
    uint8_t*  reps   = (uint8_t*)(ws + 65536);        // 8192*256 B (fp8 tiled)

    normalize_kernel<<<NPAIR / 4, 256, 0, stream>>>(emb_i, emb_j, reps,
                                                    pdot, rowsum);
    simexp_kernel<<<NQUAD, 256, 0, stream>>>(reps, rowsum);
    finalize_kernel<<<1, 256, 0, stream>>>(rowsum, pdot, out);
}

// Round 19
// 34.104 us; speedup vs baseline: 1.2872x; 1.1159x over previous
//
#include <hip/hip_runtime.h>
#include <hip/hip_fp8.h>
#include <stdint.h>

#define NPAIR 4096
#define N2    8192      // 2N rows
#define DIM   256
#define NTILE 8256      // 128*129/2 upper-triangle 64x64 tiles
// inputs pre-scaled by sqrt(log2(e)/T): acc == log2(e)/T * sim
#define SCALE_IN 1.6986436f
#define SCALE1 0x7F7F7F7F   // E8M0 1.0 in every byte (opsel-proof)

typedef int   i32x8  __attribute__((ext_vector_type(8)));
typedef float f32x16 __attribute__((ext_vector_type(16)));

static __device__ __forceinline__ uint8_t f2fp8(float f) {
    __hip_fp8_e4m3 v(f);                 // OCP e4m3fn, RNE saturating
    return *reinterpret_cast<uint8_t*>(&v);
}

// reps FRAGMENT-TILED for mfma_scale 32x32x64: byte index of (row i, dim d) =
//   ((i>>5)*4 + (d>>6))*2048 + ((i&31) + 32*((d>>5)&1))*32 + (d&31)
// A/B fragment (32 rows x 64 k; lane l -> row l&31, k-half l>>5, 32 B) is
// the contiguous 2 KB block at tile(i>>5, d>>6): lane l reads 32 B at
// base + l*32 (one i32x8 = 2x global_load_dwordx4 per fragment).

// ---------------- Kernel A: normalize rows + positive dot + zero rowsum ----
__global__ __launch_bounds__(256) void normalize_kernel(
    const float* __restrict__ emb_i, const float* __restrict__ emb_j,
    uint8_t* __restrict__ reps, float* __restrict__ pdot,
    float* __restrict__ rowsum) {
    int i = blockIdx.x * 4 + (threadIdx.x >> 6);
    int l = threadIdx.x & 63;       // 4 floats each: dims 4l..4l+3
    float4 a = ((const float4*)(emb_i + (size_t)i * DIM))[l];
    float4 b = ((const float4*)(emb_j + (size_t)i * DIM))[l];
    float si = a.x*a.x + a.y*a.y + a.z*a.z + a.w*a.w;
    float sj = b.x*b.x + b.y*b.y + b.z*b.z + b.w*b.w;
    float dp = a.x*b.x + a.y*b.y + a.z*b.z + a.w*b.w;
    #pragma unroll
    for (int off = 32; off; off >>= 1) {
        si += __shfl_xor(si, off);
        sj += __shfl_xor(sj, off);
        dp += __shfl_xor(dp, off);
    }
    float ri = 1.0f / fmaxf(sqrtf(si), 1e-12f);
    float rj = 1.0f / fmaxf(sqrtf(sj), 1e-12f);
    float riS = ri * SCALE_IN, rjS = rj * SCALE_IN;

    uchar4 ua, ub;
    ua.x = f2fp8(a.x * riS); ua.y = f2fp8(a.y * riS);
    ua.z = f2fp8(a.z * riS); ua.w = f2fp8(a.w * riS);
    ub.x = f2fp8(b.x * rjS); ub.y = f2fp8(b.y * rjS);
    ub.z = f2fp8(b.z * rjS); ub.w = f2fp8(b.w * rjS);

    // tiled store for d=4l: ktile = l>>4, khalf = (l>>3)&1, koff = (l&7)*4
    int ii = i + NPAIR;
    int inner = ((l >> 3) & 1) * 32;
    int koff  = (l & 7) * 4;
    int idxA = (((i  >> 5) * 4 + (l >> 4)) * 2048)
             + ((i  & 31) + inner) * 32 + koff;
    int idxB = (((ii >> 5) * 4 + (l >> 4)) * 2048)
             + ((ii & 31) + inner) * 32 + koff;
    *(uchar4*)(reps + idxA) = ua;
    *(uchar4*)(reps + idxB) = ub;

    if (l == 0) pdot[i] = dp * ri * rj;       // positives fp32, unscaled
    if (l < 2)  rowsum[2 * i + l] = 0.f;
}

// ---------- Kernel B: BARRIER-FREE per-wave 64x64 tiles, MX-scaled fp8 ----
// r17 structure with the GEMM core on mfma_scale_f32_32x32x64_f8f6f4
// (scales = 1.0 -> numerically identical to plain fp8, 2x the MFMA rate):
// 16 MFMA instrs/wave (4 K-steps x 2x2 32x32 tiles) vs 128. Single-buffered
// fragments (acc 64 + frags 32 VGPR < 128 @ (256,4)); TLP hides L2 latency.
// Epilogue on the 32x32 C/D layout: col=lane&31,
// row=(reg&3)+8*(reg>>2)+4*(lane>>5) [m74/m101]; butterfly multi-reduce
// (31 shuffles) for 32 row partials; 2 atomics/lane, disjoint targets.
__global__ __launch_bounds__(256, 4) void simexp_kernel(
    const uint8_t* __restrict__ reps, float* __restrict__ rowsum) {
    int t = threadIdx.x;
    int l = t & 63;

    // anti-diagonal decode over n=128 tile grid: C(d) = d*(257-d)/2
    int idx = blockIdx.x * 4 + (t >> 6);
    int d = (int)((257.0f - sqrtf(257.0f * 257.0f - 8.0f * (float)idx)) * 0.5f);
    while (d * (257 - d) / 2 > idx) --d;
    while ((d + 1) * (256 - d) / 2 <= idx) ++d;
    int i0 = idx - d * (257 - d) / 2;
    int brow = i0 * 64;
    int bcol = (i0 + d) * 64;
    int R0A = i0 * 2;               // 32-row fragment blocks (+mi)
    int R0B = (i0 + d) * 2;         // +ni

    f32x16 acc[2][2];
    #pragma unroll
    for (int mi = 0; mi < 2; ++mi)
        #pragma unroll
        for (int ni = 0; ni < 2; ++ni)
            acc[mi][ni] = (f32x16)(0.f);

    for (int ks = 0; ks < 4; ++ks) {    // 4 K-steps of 64
        i32x8 a[2], b[2];
        #pragma unroll
        for (int q = 0; q < 2; ++q) {
            a[q] = ((const i32x8*)(reps +
                    (size_t)(((R0A + q) * 4 + ks) * 2048)))[l];
            b[q] = ((const i32x8*)(reps +
                    (size_t)(((R0B + q) * 4 + ks) * 2048)))[l];
        }
        __builtin_amdgcn_s_setprio(1);
        #pragma unroll
        for (int mi = 0; mi < 2; ++mi)
            #pragma unroll
            for (int ni = 0; ni < 2; ++ni)
                acc[mi][ni] = __builtin_amdgcn_mfma_scale_f32_32x32x64_f8f6f4(
                    a[mi], b[ni], acc[mi][ni],
                    0, 0,               // cbsz=fp8, blgp=fp8
                    0, SCALE1,          // opsel_a, scale_a = 1.0
                    0, SCALE1);         // opsel_b, scale_b = 1.0
        __builtin_amdgcn_s_setprio(0);
    }

    // Epilogue. 32x32 C/D: col = lane&31, row = (v&3)+8*(v>>2)+4*(lane>>5)
    // acc already == log2(e)/T * sim -> bare exp2f.
    int c32 = l & 31;
    int h   = l >> 5;
    float csum[2] = {0.f, 0.f};

    if (d != 0) {                   // off-diagonal: unmasked, rows + cols
        float rpar[32];             // u = mi*16 + (v&3)+4*(v>>2)
        #pragma unroll
        for (int mi = 0; mi < 2; ++mi) {
            #pragma unroll
            for (int v = 0; v < 16; ++v) {
                float e0 = exp2f(acc[mi][0][v]);
                float e1 = exp2f(acc[mi][1][v]);
                csum[0] += e0;
                csum[1] += e1;
                rpar[mi * 16 + (v & 3) + 4 * (v >> 2)] = e0 + e1;
            }
        }
        // butterfly multi-reduce over the 32-lane half (bits 0..4 of c32):
        // after stage k, lane p holds values u == p (mod 2^(k+1)).
        bool s0 = (c32 & 1);
        float w16[16];
        #pragma unroll
        for (int i = 0; i < 16; ++i) {
            float keep = s0 ? rpar[2 * i + 1] : rpar[2 * i];
            float send = s0 ? rpar[2 * i]     : rpar[2 * i + 1];
            w16[i] = keep + __shfl_xor(send, 1);
        }
        bool s1 = (c32 & 2);
        float w8[8];
        #pragma unroll
        for (int i = 0; i < 8; ++i) {
            float keep = s1 ? w16[2 * i + 1] : w16[2 * i];
            float send = s1 ? w16[2 * i]     : w16[2 * i + 1];
            w8[i] = keep + __shfl_xor(send, 2);
        }
        bool s2 = (c32 & 4);
        float w4[4];
        #pragma unroll
        for (int i = 0; i < 4; ++i) {
            float keep = s2 ? w8[2 * i + 1] : w8[2 * i];
            float send = s2 ? w8[2 * i]     : w8[2 * i + 1];
            w4[i] = keep + __shfl_xor(send, 4);
        }
        bool s3 = (c32 & 8);
        float w2[2];
        #pragma unroll
        for (int i = 0; i < 2; ++i) {
            float keep = s3 ? w4[2 * i + 1] : w4[2 * i];
            float send = s3 ? w4[2 * i]     : w4[2 * i + 1];
            w2[i] = keep + __shfl_xor(send, 8);
        }
        bool s4 = (c32 & 16);
        float keep = s4 ? w2[1] : w2[0];
        float send = s4 ? w2[0] : w2[1];
        float rv = keep + __shfl_xor(send, 16);
        // lane holds row sum for u = c32: mi=u>>4, rr=u&15

        csum[0] += __shfl_xor(csum[0], 32);
        csum[1] += __shfl_xor(csum[1], 32);
        float cv = h ? csum[1] : csum[0];
        atomicAdd(&rowsum[bcol + h * 32 + c32], cv);     // 64 disjoint cols
        int grow = brow + (c32 >> 4) * 32 + (c32 & 3)
                 + 8 * ((c32 & 15) >> 2) + 4 * h;
        atomicAdd(&rowsum[grow], rv);                    // 64 disjoint rows
    } else {                        // diagonal tile: masked, cols only
        #pragma unroll
        for (int mi = 0; mi < 2; ++mi) {
            #pragma unroll
            for (int v = 0; v < 16; ++v) {
                int grow = brow + mi * 32 + (v & 3) + 8 * (v >> 2) + 4 * h;
                #pragma unroll
                for (int ni = 0; ni < 2; ++ni) {
                    float e = exp2f(acc[mi][ni][v]);
                    int gcol = bcol + ni * 32 + c32;
                    e = (grow == gcol) ? 0.f : e;        // main diagonal
                    csum[ni] += e;
                }
            }
        }
        csum[0] += __shfl_xor(csum[0], 32);
        csum[1] += __shfl_xor(csum[1], 32);
        float cv = h ? csum[1] : csum[0];
        atomicAdd(&rowsum[bcol + h * 32 + c32], cv);
    }
}

// ---------------- Kernel C: finalize ----------------
__global__ __launch_bounds__(256) void finalize_kernel(
    const float* __restrict__ rowsum, const float* __restrict__ pdot,
    float* __restrict__ out) {
    int t = threadIdx.x;
    __shared__ float reds[4], redp[4];
    const float4* rs4 = (const float4*)rowsum;
    const float4* pd4 = (const float4*)pdot;
    float s = 0.f, p = 0.f;
    for (int r = t; r < N2 / 4; r += 256) {
        float4 v = rs4[r];
        s += __logf(v.x) + __logf(v.y) + __logf(v.z) + __logf(v.w);
    }
    for (int r = t; r < NPAIR / 4; r += 256) {
        float4 v = pd4[r];
        p += v.x + v.y + v.z + v.w;
    }
    #pragma unroll
    for (int off = 32; off; off >>= 1) {
        s += __shfl_xor(s, off);
        p += __shfl_xor(p, off);
    }
    if ((t & 63) == 0) { reds[t >> 6] = s; redp[t >> 6] = p; }
    __syncthreads();
    if (t == 0) {
        float S = reds[0] + reds[1] + reds[2] + reds[3];
        float P = redp[0] + redp[1] + redp[2] + redp[3];
        // loss = (sum log D - (2/T)*2*sum(dp)) / 2N ; (2/T)*2 folded: 4*P
        out[0] = (S - 4.0f * P) / (float)N2;
    }
}

extern "C" void kernel_launch(void* const* d_in, const int* in_sizes, int n_in,
                              void* d_out, int out_size, void* d_ws, size_t ws_size,
                              hipStream_t stream) {
    const float* emb_i = (const float*)d_in[0];
    const float* emb_j = (const float*)d_in[1];
    float* out = (float*)d_out;

    char* ws = (char*)d_ws;
    float*    rowsum = (float*)ws;                    // 8192 * 4 B
    float*    pdot   = (float*)(ws + 32768);          // 4096 * 4 B
    uint8_t*  reps   = (uint8_t*)(ws + 65536);        // 8192*256 B (fp8 tiled)

    normalize_kernel<<<NPAIR / 4, 256, 0, stream>>>(emb_i, emb_j, reps,
                                                    pdot, rowsum);
    simexp_kernel<<<NTILE / 4, 256, 0, stream>>>(reps, rowsum);
    finalize_kernel<<<1, 256, 0, stream>>>(rowsum, pdot, out);
}